// Round 5
// baseline (295.027 us; speedup 1.0000x reference)
//
#include <hip/hip_runtime.h>

// out = joints @ R + t, R = RX(roll) @ RY(pitch) @ RZ(yaw), per reference.
// Streaming memory-bound op: 169 MB in + 169 MB out.
//
// v6 reasoning. v1/v3 (strided direct), v4/v5 (LDS-dense) all ~101 us at
// ~2.5 TB/s mixed; the write-only poison fill saturates 6.6 TB/s with the
// same one-shot structure. The asymmetry: stores are fire-and-forget,
// LOADS must be waited on. All previous variants were one-shot -- each
// wave issues its loads once, eats full HBM latency, computes, dies; the
// fraction of wave-lifetime with loads in flight is <=50% (worse with
// block barriers). Little's law: ~15+ KB of reads continuously in flight
// per CU are needed to saturate; one-shot waves never sustain that. The
// read stream, not bytes or pattern, is the cap -- consistent with every
// counter (VALU 2-8%, LDS 0, WRITE ideal, FETCH 85 MB, HBM 31%).
//
// Fix: persistent grid-stride kernel + register double-buffer prefetch.
// Each thread loops over ~7 tiles (3x float4 = 4 points each); next tile's
// loads issue BEFORE current tile's FMAs+stores, so steady state is
// global_load x3 -> s_waitcnt vmcnt(3) -> fma/store: loads outstanding
// ~100% of wave lifetime. No LDS, no barriers.
//  - KEEP __sinf/__cosf, regular (write-back, L2-merging) stores.

using f4 = __attribute__((ext_vector_type(4))) float;

#define BLOCK 256
#define MAX_BLOCKS 2048   // 8 blocks/CU on 256 CUs, persistent

__global__ __launch_bounds__(BLOCK) void Transform_38723425141290_kernel(
    const float* __restrict__ joints,
    const float* __restrict__ orient,
    const float* __restrict__ trans,
    float* __restrict__ out,
    long long n_groups,   // number of 4-point (3x float4) groups
    long long n_points)
{
    // --- rotation matrix (wave-uniform; tiny cached reads) ---
    const float roll = orient[0], pitch = orient[1], yaw = orient[2];
    const float sr = __sinf(roll),  cr = __cosf(roll);
    const float sp = __sinf(pitch), cp = __cosf(pitch);
    const float sy = __sinf(yaw),   cy = __cosf(yaw);

    const float R00 = cp * cy;
    const float R01 = -cp * sy;
    const float R02 = sp;
    const float R10 = sr * sp * cy + cr * sy;
    const float R11 = cr * cy - sr * sp * sy;
    const float R12 = -sr * cp;
    const float R20 = sr * sy - cr * sp * cy;
    const float R21 = cr * sp * sy + sr * cy;
    const float R22 = cr * cp;

    const float tx = trans[0], ty = trans[1], tz = trans[2];

    const long long stride = (long long)gridDim.x * blockDim.x;
    long long g = (long long)blockIdx.x * blockDim.x + threadIdx.x;

    const f4* __restrict__ jp = reinterpret_cast<const f4*>(joints);
    f4* __restrict__ op = reinterpret_cast<f4*>(out);

    if (g < n_groups) {
        // prime the pipeline: tile 0 in flight
        f4 a = jp[g * 3 + 0];
        f4 b = jp[g * 3 + 1];
        f4 c = jp[g * 3 + 2];

        for (;;) {
            // issue NEXT tile's loads before touching current tile's data:
            // the s_waitcnt for (a,b,c) lands after these issue -> loads
            // stay continuously in flight.
            const long long gn = g + stride;
            const bool more = (gn < n_groups);
            f4 a2, b2, c2;
            if (more) {
                a2 = jp[gn * 3 + 0];
                b2 = jp[gn * 3 + 1];
                c2 = jp[gn * 3 + 2];
            }

            f4 o0, o1, o2;
            #define ROT(x, y, z, ox, oy, oz)              \
                ox = x * R00 + y * R10 + z * R20 + tx;    \
                oy = x * R01 + y * R11 + z * R21 + ty;    \
                oz = x * R02 + y * R12 + z * R22 + tz;

            // 4 points from 12 consecutive floats
            ROT(a.x, a.y, a.z, o0.x, o0.y, o0.z)
            ROT(a.w, b.x, b.y, o0.w, o1.x, o1.y)
            ROT(b.z, b.w, c.x, o1.z, o1.w, o2.x)
            ROT(c.y, c.z, c.w, o2.y, o2.z, o2.w)
            #undef ROT

            // fire-and-forget stores (regular: L2 merges the 48B strides)
            op[g * 3 + 0] = o0;
            op[g * 3 + 1] = o1;
            op[g * 3 + 2] = o2;

            if (!more) break;
            g = gn;
            a = a2; b = b2; c = c2;
        }
    }

    // scalar tail (n_points % 4 != 0) — dead for this shape, kept for safety
    const long long tail_base = n_groups * 4;
    const long long t0 = (long long)blockIdx.x * blockDim.x + threadIdx.x;
    if (t0 < (n_points - tail_base)) {
        const long long i = tail_base + t0;
        const float x = joints[i * 3 + 0];
        const float y = joints[i * 3 + 1];
        const float z = joints[i * 3 + 2];
        out[i * 3 + 0] = x * R00 + y * R10 + z * R20 + tx;
        out[i * 3 + 1] = x * R01 + y * R11 + z * R21 + ty;
        out[i * 3 + 2] = x * R02 + y * R12 + z * R22 + tz;
    }
}

extern "C" void kernel_launch(void* const* d_in, const int* in_sizes, int n_in,
                              void* d_out, int out_size, void* d_ws, size_t ws_size,
                              hipStream_t stream) {
    const float* joints = (const float*)d_in[0];
    const float* orient = (const float*)d_in[1];
    const float* trans  = (const float*)d_in[2];
    float* out = (float*)d_out;

    const long long n_floats = (long long)in_sizes[0];
    const long long n_points = n_floats / 3;
    const long long n_groups = n_points / 4;

    long long blocks = (n_groups + BLOCK - 1) / BLOCK;
    if (blocks > MAX_BLOCKS) blocks = MAX_BLOCKS;
    if (blocks < 1) blocks = 1;

    Transform_38723425141290_kernel<<<dim3((unsigned)blocks), dim3(BLOCK), 0, stream>>>(
        joints, orient, trans, out, n_groups, n_points);
}